// Round 4
// baseline (1548.733 us; speedup 1.0000x reference)
//
#include <hip/hip_runtime.h>
#include <stdint.h>

#define N_UPDATE 3
#define HD 32
#define FN 16

typedef unsigned short u16;
typedef __bf16 bf16x8 __attribute__((ext_vector_type(8)));
typedef float f32x4 __attribute__((ext_vector_type(4)));

__device__ __forceinline__ float bf2f(u16 u) {
  union { uint32_t i; float f; } v; v.i = ((uint32_t)u) << 16; return v.f;
}
__device__ __forceinline__ u16 f2bf(float f) {
  union { uint32_t i; float f; } v; v.f = f;
  uint32_t x = v.i;
  return (u16)((x + 0x7fffu + ((x >> 16) & 1u)) >> 16);  // RNE
}

union frag16 { uint4 v; bf16x8 b; u16 s[8]; };

__global__ void k_zero(float* __restrict__ p, int n) {
  int i = blockIdx.x * blockDim.x + threadIdx.x;
  if (i < n) p[i] = 0.f;
}

// ---------------- Bf[t][lane]: MFMA B-fragments for the G-GEMM (128 column-tiles of 16).
// G[n][j] = sum_h h[n][h] * B[h][j],  j=o*64+kk,  B[h][j] = Wm2[kk][h*32+o]
__global__ void k_prep_bf(const float* __restrict__ Wm2, uint4* __restrict__ Bf) {
  int t = blockIdx.x;       // 128
  int lane = threadIdx.x;   // 64
  int col = lane & 15;
  int hg = lane >> 4;
  frag16 f;
#pragma unroll
  for (int jj = 0; jj < 8; jj++) {
    int h = hg * 8 + jj;
    int j = t * 16 + col;
    int kk = j & 63;
    int o = j >> 6;
    f.s[jj] = f2bf(Wm2[kk * 1024 + h * 32 + o]);
  }
  Bf[t * 64 + lane] = f.v;
}

// ---------------- h0 init
__global__ void k_init_h(const float* __restrict__ x, float* __restrict__ h, int N) {
  int idx = blockIdx.x * blockDim.x + threadIdx.x;
  if (idx >= N * HD) return;
  int n = idx >> 5, c = idx & 31;
  h[idx] = (c < FN) ? x[n * FN + c] : 0.f;
}

// ---------------- edge MLP (2 layers, relu) -> ee bf16 [E][64]
__global__ __launch_bounds__(256) void k_edge_mlp(
    const float* __restrict__ ea,
    const float* __restrict__ Wm0, const float* __restrict__ bm0,
    const float* __restrict__ Wm1, const float* __restrict__ bm1,
    u16* __restrict__ ee, int E) {
  int e = blockIdx.x * blockDim.x + threadIdx.x;
  if (e >= E) return;
  float a[16];
  {
    const float4* p = (const float4*)(ea + (size_t)e * 16);
    float4 v0 = p[0], v1 = p[1], v2 = p[2], v3 = p[3];
    a[0]=v0.x; a[1]=v0.y; a[2]=v0.z; a[3]=v0.w;
    a[4]=v1.x; a[5]=v1.y; a[6]=v1.z; a[7]=v1.w;
    a[8]=v2.x; a[9]=v2.y; a[10]=v2.z; a[11]=v2.w;
    a[12]=v3.x; a[13]=v3.y; a[14]=v3.z; a[15]=v3.w;
  }
  float t0[64];
#pragma unroll
  for (int j = 0; j < 64; j++) t0[j] = bm0[j];
#pragma unroll
  for (int k = 0; k < 16; k++) {
    float av = a[k];
#pragma unroll
    for (int j = 0; j < 64; j++) t0[j] = fmaf(av, Wm0[k * 64 + j], t0[j]);
  }
#pragma unroll
  for (int j = 0; j < 64; j++) t0[j] = fmaxf(t0[j], 0.f);

#pragma unroll
  for (int half = 0; half < 2; half++) {
    float t1[32];
#pragma unroll
    for (int j = 0; j < 32; j++) t1[j] = bm1[half * 32 + j];
#pragma unroll
    for (int k = 0; k < 64; k++) {
      float tv = t0[k];
#pragma unroll
      for (int j = 0; j < 32; j++) t1[j] = fmaf(tv, Wm1[k * 64 + half * 32 + j], t1[j]);
    }
    unsigned int out[16];
#pragma unroll
    for (int j = 0; j < 16; j++) {
      u16 lo = f2bf(fmaxf(t1[2 * j], 0.f));
      u16 hi = f2bf(fmaxf(t1[2 * j + 1], 0.f));
      out[j] = (unsigned int)lo | ((unsigned int)hi << 16);
    }
    uint4* op = (uint4*)(ee + (size_t)e * 64 + half * 32);
#pragma unroll
    for (int q = 0; q < 4; q++) {
      uint4 w; w.x = out[q*4+0]; w.y = out[q*4+1]; w.z = out[q*4+2]; w.w = out[q*4+3];
      op[q] = w;
    }
  }
}

// ---------------- hb[n][o] = sum_h h[n][h] * bm2[h*32+o]
__global__ __launch_bounds__(256) void k_hb(
    const float* __restrict__ h, const float* __restrict__ bm2,
    float* __restrict__ hb, int N) {
  int t = blockIdx.x * blockDim.x + threadIdx.x;
  int n = t >> 5, o = t & 31;
  if (n >= N) return;
  float hv = h[(size_t)n * HD + o];
  float acc = 0.f;
#pragma unroll
  for (int k = 0; k < 32; k++)
    acc = fmaf(__shfl(hv, k, 32), bm2[k * 32 + o], acc);
  hb[(size_t)n * HD + o] = acc;
}

// ---------------- G GEMM for an o-chunk: Gb[n][o_l][k] bf16, o_l in [0,OC)
__global__ __launch_bounds__(256) void k_gemm_G(
    const float* __restrict__ h, const uint4* __restrict__ Bf,
    u16* __restrict__ Gb, int N, int o_base, int OC) {
  int wave = threadIdx.x >> 6;
  int lane = threadIdx.x & 63;
  int jt = o_base * 4 + blockIdx.y * 4 + wave;  // blockIdx.y < OC  -> jt < (o_base+OC)*4 <= 128
  int n0 = blockIdx.x * 16;
  int row = lane & 15;
  int kg = lane >> 4;

  int nr = n0 + row; if (nr > N - 1) nr = N - 1;
  const float* hr = h + (size_t)nr * HD + kg * 8;
  float4 f0 = *(const float4*)hr;
  float4 f1 = *(const float4*)(hr + 4);
  frag16 a;
  a.s[0] = f2bf(f0.x); a.s[1] = f2bf(f0.y); a.s[2] = f2bf(f0.z); a.s[3] = f2bf(f0.w);
  a.s[4] = f2bf(f1.x); a.s[5] = f2bf(f1.y); a.s[6] = f2bf(f1.z); a.s[7] = f2bf(f1.w);

  frag16 b; b.v = Bf[jt * 64 + lane];

  f32x4 acc = {0.f, 0.f, 0.f, 0.f};
  acc = __builtin_amdgcn_mfma_f32_16x16x32_bf16(a.b, b.b, acc, 0, 0, 0);

  int j = jt * 16 + row;           // global column; o = j>>6, k = j&63
  int o_l = (j >> 6) - o_base;
  int k = j & 63;
#pragma unroll
  for (int r = 0; r < 4; r++) {
    int n = n0 + kg * 4 + r;
    if (n < N) Gb[((size_t)n * OC + o_l) * 64 + k] = f2bf(acc[r]);
  }
}

// ---------------- msg for an o-chunk: lane o_l of OC per edge
__global__ __launch_bounds__(256) void k_msg(
    const u16* __restrict__ Gb, const float* __restrict__ hb,
    const u16* __restrict__ ee, const int* __restrict__ eidx,
    float* __restrict__ agg, int E, int o_base, int ocShift) {
  int t = blockIdx.x * blockDim.x + threadIdx.x;
  int e = t >> ocShift;
  int o_l = t & ((1 << ocShift) - 1);
  if (e >= E) return;
  const int2 sd = ((const int2*)eidx)[e];
  int o = o_base + o_l;

  float acc = hb[(size_t)sd.x * HD + o];

  const uint4* ep = (const uint4*)(ee + (size_t)e * 64);
  const uint4* gp = (const uint4*)(Gb + (((size_t)sd.x << ocShift) + o_l) * 64);
  frag16 eu[8], gu[8];
#pragma unroll
  for (int q = 0; q < 8; q++) { eu[q].v = ep[q]; gu[q].v = gp[q]; }
#pragma unroll
  for (int k = 0; k < 64; k++) {
    acc = fmaf(bf2f(eu[k >> 3].s[k & 7]), bf2f(gu[k >> 3].s[k & 7]), acc);
  }
  atomicAdd(&agg[(size_t)sd.y * HD + o], acc);
}

// ---------------- node update
__global__ __launch_bounds__(256) void k_update(
    const float* __restrict__ h, const float* __restrict__ agg,
    const float* __restrict__ root, const float* __restrict__ bias,
    float* __restrict__ hn, int N) {
  int t = blockIdx.x * blockDim.x + threadIdx.x;
  int n = t >> 5, o = t & 31;
  if (n >= N) return;
  float hv = h[(size_t)n * HD + o];
  float acc = bias[o] + agg[(size_t)n * HD + o];
#pragma unroll
  for (int k = 0; k < 32; k++)
    acc = fmaf(__shfl(hv, k, 32), root[k * HD + o], acc);
  hn[(size_t)n * HD + o] = acc;
}

// ---------------- readout
__global__ __launch_bounds__(256) void k_readout(
    const float* __restrict__ h, const float* __restrict__ x,
    const float* __restrict__ Wi0, const float* __restrict__ bi0,
    const float* __restrict__ Wi1, const float* __restrict__ bi1,
    const float* __restrict__ Wj0, const float* __restrict__ bj0,
    const float* __restrict__ Wj1, const float* __restrict__ bj1,
    float* __restrict__ partial, int N) {
  int wid = threadIdx.x >> 6;
  int lane = threadIdx.x & 63;
  int n = blockIdx.x * 4 + wid;
  __shared__ float sred[4];
  float contrib = 0.f;
  if (n < N) {
    float uv;
    if (lane < 32) uv = h[(size_t)n * HD + lane];
    else if (lane < 48) uv = x[(size_t)n * FN + lane - 32];
    else uv = 0.f;

    float g1a = bi0[lane], g1b = bi0[lane + 64];
#pragma unroll
    for (int k = 0; k < 64; k++) {
      float u = __shfl(uv, k, 64);
      g1a = fmaf(u, Wi0[k * 128 + lane], g1a);
      g1b = fmaf(u, Wi0[k * 128 + lane + 64], g1b);
    }
    g1a = fmaxf(g1a, 0.f); g1b = fmaxf(g1b, 0.f);
    float gp = g1a * Wi1[lane] + g1b * Wi1[lane + 64];

    float v1a = bj0[lane], v1b = bj0[lane + 64];
#pragma unroll
    for (int k = 0; k < 32; k++) {
      float hk = __shfl(uv, k, 64);
      v1a = fmaf(hk, Wj0[k * 128 + lane], v1a);
      v1b = fmaf(hk, Wj0[k * 128 + lane + 64], v1b);
    }
    v1a = fmaxf(v1a, 0.f); v1b = fmaxf(v1b, 0.f);
    float vp = v1a * Wj1[lane] + v1b * Wj1[lane + 64];

#pragma unroll
    for (int s = 32; s; s >>= 1) {
      gp += __shfl_xor(gp, s, 64);
      vp += __shfl_xor(vp, s, 64);
    }
    float gate = 1.f / (1.f + __expf(-(gp + bi1[0])));
    float val = vp + bj1[0];
    contrib = gate * val;
  }
  if (lane == 0) sred[wid] = contrib;
  __syncthreads();
  if (threadIdx.x == 0) partial[blockIdx.x] = sred[0] + sred[1] + sred[2] + sred[3];
}

__global__ void k_final(const float* __restrict__ partial, float* __restrict__ out, int P) {
  __shared__ float sm[256];
  float s = 0.f;
  for (int i = threadIdx.x; i < P; i += 256) s += partial[i];
  sm[threadIdx.x] = s;
  __syncthreads();
  for (int st = 128; st; st >>= 1) {
    if ((int)threadIdx.x < st) sm[threadIdx.x] += sm[threadIdx.x + st];
    __syncthreads();
  }
  if (threadIdx.x == 0) out[0] = sm[0];
}

extern "C" void kernel_launch(void* const* d_in, const int* in_sizes, int n_in,
                              void* d_out, int out_size, void* d_ws, size_t ws_size,
                              hipStream_t stream) {
  const float* x    = (const float*)d_in[0];
  const int*   eidx = (const int*)d_in[1];
  const float* ea   = (const float*)d_in[2];
  const float* Wm0  = (const float*)d_in[3];
  const float* bm0  = (const float*)d_in[4];
  const float* Wm1  = (const float*)d_in[5];
  const float* bm1  = (const float*)d_in[6];
  const float* Wm2  = (const float*)d_in[7];
  const float* bm2  = (const float*)d_in[8];
  const float* root = (const float*)d_in[9];
  const float* bias = (const float*)d_in[10];
  const float* Wi0  = (const float*)d_in[11];
  const float* bi0  = (const float*)d_in[12];
  const float* Wi1  = (const float*)d_in[13];
  const float* bi1  = (const float*)d_in[14];
  const float* Wj0  = (const float*)d_in[15];
  const float* bj0  = (const float*)d_in[16];
  const float* Wj1  = (const float*)d_in[17];
  const float* bj1  = (const float*)d_in[18];

  int N = in_sizes[0] / FN;
  int E = in_sizes[1] / 2;
  int nb = (N + 3) / 4;

  auto al = [](size_t b) { return (b + 255) & ~(size_t)255; };
  size_t ee_b = al((size_t)E * 64 * 2);
  size_t bf_b = al(128 * 64 * sizeof(uint4));
  size_t nv_b = al((size_t)N * HD * 4);   // hb / hA / hB / agg each
  size_t pa_b = al((size_t)nb * 4);
  size_t fixed = ee_b + bf_b + 4 * nv_b + pa_b;

  // pick largest o-chunk OC in {32,16,8,4} whose Gb fits the workspace
  int OC = 0, ocShift = 0;
  for (int c = 32, s = 5; c >= 4; c >>= 1, s--) {
    size_t gb_b = al((size_t)N * c * 64 * 2);
    if (fixed + gb_b <= ws_size) { OC = c; ocShift = s; break; }
  }
  if (OC == 0) return;  // workspace too small: do nothing (diagnostic beacon)

  char* ws = (char*)d_ws;
  size_t off = 0;
  auto alloc = [&](size_t bytes) { void* p = ws + off; off += al(bytes); return p; };
  u16*   Gb      = (u16*)alloc((size_t)N * OC * 64 * 2);
  u16*   ee      = (u16*)alloc((size_t)E * 64 * 2);
  uint4* Bf      = (uint4*)alloc(128 * 64 * sizeof(uint4));
  float* hb      = (float*)alloc((size_t)N * HD * 4);
  float* hA      = (float*)alloc((size_t)N * HD * 4);
  float* hB      = (float*)alloc((size_t)N * HD * 4);
  float* agg     = (float*)alloc((size_t)N * HD * 4);
  float* partial = (float*)alloc((size_t)nb * 4);

  int mt = (N + 15) / 16;
  int nwarp_grid = (N * HD + 255) / 256;

  hipLaunchKernelGGL(k_prep_bf, dim3(128), dim3(64), 0, stream, Wm2, Bf);
  hipLaunchKernelGGL(k_init_h, dim3(nwarp_grid), dim3(256), 0, stream, x, hA, N);
  hipLaunchKernelGGL(k_edge_mlp, dim3((E + 255) / 256), dim3(256), 0, stream,
                     ea, Wm0, bm0, Wm1, bm1, ee, E);

  float* hc = hA; float* hn = hB;
  for (int it = 0; it < N_UPDATE; it++) {
    hipLaunchKernelGGL(k_zero, dim3(nwarp_grid), dim3(256), 0, stream, agg, N * HD);
    hipLaunchKernelGGL(k_hb, dim3(nwarp_grid), dim3(256), 0, stream, hc, bm2, hb, N);
    for (int ob = 0; ob < HD; ob += OC) {
      hipLaunchKernelGGL(k_gemm_G, dim3(mt, OC), dim3(256), 0, stream, hc, Bf, Gb, N, ob, OC);
      hipLaunchKernelGGL(k_msg, dim3(((size_t)E * OC + 255) / 256), dim3(256), 0, stream,
                         Gb, hb, ee, eidx, agg, E, ob, ocShift);
    }
    hipLaunchKernelGGL(k_update, dim3(nwarp_grid), dim3(256), 0, stream,
                       hc, agg, root, bias, hn, N);
    float* tmp = hc; hc = hn; hn = tmp;
  }

  hipLaunchKernelGGL(k_readout, dim3(nb), dim3(256), 0, stream,
                     hc, x, Wi0, bi0, Wi1, bi1, Wj0, bj0, Wj1, bj1, partial, N);
  hipLaunchKernelGGL(k_final, dim3(1), dim3(256), 0, stream, partial, (float*)d_out, nb);
}